// Round 2
// baseline (998.344 us; speedup 1.0000x reference)
//
#include <hip/hip_runtime.h>
#include <hip/hip_bf16.h>
#include <stdint.h>

#define NCLOTHES 50000
#define CPAD     50048   // 391 * 128
#define FDIM     256
#define NBATCH   1024
#define SCALEF   16.0f
#define EPSW     0.1f
#define MAXPOS   1024

typedef __attribute__((ext_vector_type(8))) short short8;
typedef __attribute__((ext_vector_type(4))) float f32x4;

__device__ __forceinline__ void gload_lds16(const void* gsrc, void* ldst) {
    __builtin_amdgcn_global_load_lds(
        (const __attribute__((address_space(1))) void*)gsrc,
        (__attribute__((address_space(3))) void*)ldst, 16, 0, 0);
}

__global__ void zero_kernel(float* negsum, int* poscount) {
    int i = blockIdx.x * blockDim.x + threadIdx.x;
    if (i < NBATCH) { negsum[i] = 0.f; poscount[i] = 0; }
}

// inputs_norm * SCALE -> bf16 A [1024][256]; one block (256 thr) per row
__global__ void anorm_kernel(const float* __restrict__ in, __hip_bfloat16* __restrict__ A) {
    int b = blockIdx.x, t = threadIdx.x;
    float x = in[b * FDIM + t];
    float ss = x * x;
    #pragma unroll
    for (int o = 32; o > 0; o >>= 1) ss += __shfl_xor(ss, o);
    __shared__ float sh[4];
    if ((t & 63) == 0) sh[t >> 6] = ss;
    __syncthreads();
    float tot = sh[0] + sh[1] + sh[2] + sh[3];
    float r = SCALEF / fmaxf(sqrtf(tot), 1e-12f);
    A[b * FDIM + t] = __float2bfloat16(x * r);
}

// scatter-mean (gather form) + l2-normalize -> bf16 B [CPAD][256]; block per clothes id
__global__ void bnorm_kernel(const float* __restrict__ fm, const float* __restrict__ in,
                             const int* __restrict__ tg, __hip_bfloat16* __restrict__ Bm) {
    int c = blockIdx.x, t = threadIdx.x;
    __shared__ int stg[NBATCH];
    if (c < NCLOTHES) {
        #pragma unroll
        for (int j = 0; j < 4; ++j) stg[t + j * 256] = tg[t + j * 256];
    }
    if (c >= NCLOTHES) { Bm[(size_t)c * FDIM + t] = __float2bfloat16(0.f); return; }
    __shared__ int mlist[32];
    __shared__ int mcount;
    if (t == 0) mcount = 0;
    __syncthreads();
    #pragma unroll
    for (int j = 0; j < 4; ++j) {
        int b = t + j * 256;
        if (stg[b] == c) { int p = atomicAdd(&mcount, 1); if (p < 32) mlist[p] = b; }
    }
    __syncthreads();
    int n = mcount;
    float v;
    if (n == 0) {
        v = fm[(size_t)c * FDIM + t];
    } else {
        v = 0.f;
        for (int i = 0; i < n; ++i) v += in[mlist[i] * FDIM + t];
        v /= (float)n;
    }
    float ss = v * v;
    #pragma unroll
    for (int o = 32; o > 0; o >>= 1) ss += __shfl_xor(ss, o);
    __shared__ float sh[4];
    if ((t & 63) == 0) sh[t >> 6] = ss;
    __syncthreads();
    float tot = sh[0] + sh[1] + sh[2] + sh[3];
    float r = 1.0f / fmaxf(sqrtf(tot), 1e-12f);
    Bm[(size_t)c * FDIM + t] = __float2bfloat16(v * r);
}

// Fused GEMM: sims tile [128x128]; epilogue re-layouts sims through LDS and
// streams pm with coalesced float4 loads prefetched one 32-row chunk ahead.
#define BM 128
#define BN 128
#define BK 32
#define NKSTEP (FDIM / BK)

__global__ __launch_bounds__(256, 2)
void gemm_kernel(const __hip_bfloat16* __restrict__ A, const __hip_bfloat16* __restrict__ Bm,
                 const float* __restrict__ pm, float* __restrict__ negsum,
                 int* __restrict__ poscount, float2* __restrict__ posbuf) {
    // 32 KB: As[2][64*32*... ] (16 KB) + Bs (16 KB); overlaid by sims[32][132] after K-loop
    __shared__ alignas(16) char smem[32768];
    __hip_bfloat16* As0 = (__hip_bfloat16*)smem;            // As[2][BM*BK], 16 KB
    __hip_bfloat16* Bs0 = (__hip_bfloat16*)(smem + 16384);  // Bs[2][BM*BK], 16 KB
    float* sims = (float*)smem;                             // [32][132] f32, 16.9 KB

    const int t = threadIdx.x;
    const int bn0 = blockIdx.x * BN;
    const int bm0 = blockIdx.y * BM;

    const int lane = t & 63;
    const int wave = t >> 6;
    const int wr = wave >> 1, wc = wave & 1;
    const int lrow = lane & 15, lq = lane >> 4;

    const int sr = t >> 2;            // staging row 0..63
    const int sk = (t & 3) * 8;       // staging k chunk

    // epilogue flat-order coordinates
    const int trow = t >> 5;          // 0..7
    const int tcol = (t & 31) * 4;    // 0..124

    f32x4 acc[4][4];
    #pragma unroll
    for (int m = 0; m < 4; ++m)
        #pragma unroll
        for (int n = 0; n < 4; ++n) acc[m][n] = (f32x4)0.f;

    // prefetch pm chunk 0 (rounds 0..3) — latency hidden under the K-loop
    f32x4 pva[4], pvb[4];
    {
        const int gcol0 = bn0 + tcol;
        #pragma unroll
        for (int j = 0; j < 4; ++j) {
            int grow = bm0 + j * 8 + trow;
            pva[j] = (gcol0 < NCLOTHES)
                ? *(const f32x4*)(pm + (size_t)grow * NCLOTHES + gcol0)
                : (f32x4)0.f;
        }
    }

    // stage k-step 0 into buffer 0
    {
        const __hip_bfloat16* ag = A + (size_t)(bm0 + sr) * FDIM + sk;
        const __hip_bfloat16* bg = Bm + (size_t)(bn0 + sr) * FDIM + sk;
        gload_lds16(ag,             (void*)&As0[t * 8]);
        gload_lds16(ag + 64 * FDIM, (void*)&As0[2048 + t * 8]);
        gload_lds16(bg,             (void*)&Bs0[t * 8]);
        gload_lds16(bg + 64 * FDIM, (void*)&Bs0[2048 + t * 8]);
    }

    for (int ks = 0; ks < NKSTEP; ++ks) {
        __syncthreads();
        int cur = ks & 1;
        if (ks + 1 < NKSTEP) {
            int nxt = cur ^ 1;
            int k0 = (ks + 1) * BK;
            const __hip_bfloat16* ag = A + (size_t)(bm0 + sr) * FDIM + k0 + sk;
            const __hip_bfloat16* bg = Bm + (size_t)(bn0 + sr) * FDIM + k0 + sk;
            gload_lds16(ag,             (void*)&As0[nxt * 4096 + t * 8]);
            gload_lds16(ag + 64 * FDIM, (void*)&As0[nxt * 4096 + 2048 + t * 8]);
            gload_lds16(bg,             (void*)&Bs0[nxt * 4096 + t * 8]);
            gload_lds16(bg + 64 * FDIM, (void*)&Bs0[nxt * 4096 + 2048 + t * 8]);
        }
        short8 af[4], bf[4];
        #pragma unroll
        for (int m = 0; m < 4; ++m)
            af[m] = *(const short8*)&As0[cur * 4096 + (wr * 64 + m * 16 + lrow) * BK + lq * 8];
        #pragma unroll
        for (int n = 0; n < 4; ++n)
            bf[n] = *(const short8*)&Bs0[cur * 4096 + (wc * 64 + n * 16 + lrow) * BK + lq * 8];
        #pragma unroll
        for (int m = 0; m < 4; ++m)
            #pragma unroll
            for (int n = 0; n < 4; ++n)
                acc[m][n] = __builtin_amdgcn_mfma_f32_16x16x32_bf16(af[m], bf[n], acc[m][n], 0, 0, 0);
    }

    __syncthreads();   // all MFMA LDS reads done before overlaying sims

    const int gcol0 = bn0 + tcol;
    // 4 chunks of 32 rows; C/D layout: tile row = wr*64 + m*16 + lq*4 + r, col = wc*64 + n*16 + lrow
    #pragma unroll
    for (int c = 0; c < 4; ++c) {
        // store this chunk's acc slice to LDS (waves with wr == c>>1 own it)
        if (wr == (c >> 1)) {
            #pragma unroll
            for (int mm = 0; mm < 2; ++mm) {
                int m = (c & 1) * 2 + mm;
                #pragma unroll
                for (int n = 0; n < 4; ++n) {
                    int col = wc * 64 + n * 16 + lrow;
                    #pragma unroll
                    for (int r = 0; r < 4; ++r) {
                        int rloc = mm * 16 + lq * 4 + r;
                        sims[rloc * 132 + col] = acc[m][n][r];
                    }
                }
            }
        }
        // prefetch next chunk's pm
        if (c < 3) {
            f32x4* dst = (c & 1) ? pva : pvb;
            #pragma unroll
            for (int j = 0; j < 4; ++j) {
                int grow = bm0 + (c + 1) * 32 + j * 8 + trow;
                dst[j] = (gcol0 < NCLOTHES)
                    ? *(const f32x4*)(pm + (size_t)grow * NCLOTHES + gcol0)
                    : (f32x4)0.f;
            }
        }
        __syncthreads();   // sims chunk visible
        const f32x4* pv = (c & 1) ? pvb : pva;
        #pragma unroll
        for (int j = 0; j < 4; ++j) {
            int row = j * 8 + trow;               // row within chunk (0..31)
            int grow = bm0 + c * 32 + row;
            f32x4 s4 = *(const f32x4*)&sims[row * 132 + tcol];
            f32x4 p4 = pv[j];
            float pneg = 0.f;
            if (gcol0 < NCLOTHES) {
                #pragma unroll
                for (int i = 0; i < 4; ++i) {
                    float e = __expf(s4[i]);
                    if (p4[i] >= 0.5f) {
                        int slot = atomicAdd(&poscount[grow], 1);
                        if (slot < MAXPOS)
                            posbuf[(size_t)grow * MAXPOS + slot] =
                                make_float2(s4[i], __int_as_float(gcol0 + i));
                    } else {
                        pneg += e;
                    }
                }
            }
            #pragma unroll
            for (int o = 1; o < 32; o <<= 1) pneg += __shfl_xor(pneg, o);
            if ((lane & 31) == 0) atomicAdd(&negsum[grow], pneg);
        }
        __syncthreads();   // sims consumed before next chunk's store
    }
}

__global__ void finish_kernel(const float* __restrict__ negsum, const int* __restrict__ poscount,
                              const float2* __restrict__ posbuf, const int* __restrict__ tg,
                              float* __restrict__ loss_rows) {
    int b = blockIdx.x, t = threadIdx.x;
    float ns = negsum[b];
    int n = poscount[b];
    if (n > MAXPOS) n = MAXPOS;
    int tgt = tg[b];
    float slp = 0.f, idlp = 0.f;
    for (int i = t; i < n; i += 256) {
        float2 v = posbuf[(size_t)b * MAXPOS + i];
        float s = v.x;
        int c = __float_as_int(v.y);
        float lp = s - __logf(ns + __expf(s));
        slp += lp;
        if (c == tgt) idlp = lp;
    }
    #pragma unroll
    for (int o = 32; o > 0; o >>= 1) { slp += __shfl_xor(slp, o); idlp += __shfl_xor(idlp, o); }
    __shared__ float sh1[4], sh2[4];
    if ((t & 63) == 0) { sh1[t >> 6] = slp; sh2[t >> 6] = idlp; }
    __syncthreads();
    if (t == 0) {
        float s_all = sh1[0] + sh1[1] + sh1[2] + sh1[3];
        float i_all = sh2[0] + sh2[1] + sh2[2] + sh2[3];
        loss_rows[b] = -((1.0f - EPSW) * i_all + (EPSW / (float)n) * s_all);
    }
}

__global__ void reduce_kernel(const float* __restrict__ lr, float* __restrict__ out) {
    int t = threadIdx.x;
    float s = lr[t] + lr[t + 256] + lr[t + 512] + lr[t + 768];
    #pragma unroll
    for (int o = 32; o > 0; o >>= 1) s += __shfl_xor(s, o);
    __shared__ float sh[4];
    if ((t & 63) == 0) sh[t >> 6] = s;
    __syncthreads();
    if (t == 0) out[0] = (sh[0] + sh[1] + sh[2] + sh[3]) * (1.0f / NBATCH);
}

extern "C" void kernel_launch(void* const* d_in, const int* in_sizes, int n_in,
                              void* d_out, int out_size, void* d_ws, size_t ws_size,
                              hipStream_t stream) {
    const float* inputs  = (const float*)d_in[0];
    const float* fm      = (const float*)d_in[1];
    const float* pmask   = (const float*)d_in[2];
    const int*   targets = (const int*)d_in[3];
    float* out = (float*)d_out;

    char* ws = (char*)d_ws;
    size_t off = 0;
    __hip_bfloat16* A = (__hip_bfloat16*)(ws + off);  off += (size_t)NBATCH * FDIM * 2;       // 512 KB
    __hip_bfloat16* Bm = (__hip_bfloat16*)(ws + off); off += (size_t)CPAD * FDIM * 2;         // 25.6 MB
    off = (off + 255) & ~(size_t)255;
    float* negsum = (float*)(ws + off);    off += 4096;
    int* poscount = (int*)(ws + off);      off += 4096;
    float* loss_rows = (float*)(ws + off); off += 4096;
    float2* posbuf = (float2*)(ws + off);  off += (size_t)NBATCH * MAXPOS * sizeof(float2);   // 8 MB

    zero_kernel<<<8, 256, 0, stream>>>(negsum, poscount);
    anorm_kernel<<<NBATCH, 256, 0, stream>>>(inputs, A);
    bnorm_kernel<<<CPAD, 256, 0, stream>>>(fm, inputs, targets, Bm);
    gemm_kernel<<<dim3(CPAD / BN, NBATCH / BM), 256, 0, stream>>>(A, Bm, pmask, negsum, poscount, posbuf);
    finish_kernel<<<NBATCH, 256, 0, stream>>>(negsum, poscount, posbuf, targets, loss_rows);
    reduce_kernel<<<1, 256, 0, stream>>>(loss_rows, out);
}

// Round 3
// 419.466 us; speedup vs baseline: 2.3800x; 2.3800x over previous
//
#include <hip/hip_runtime.h>
#include <hip/hip_bf16.h>
#include <stdint.h>

#define NCLOTHES 50000
#define CPAD     50048   // 391 * 128
#define NCB      391     // number of 128-col blocks
#define FDIM     256
#define NBATCH   1024
#define SCALEF   16.0f
#define EPSW     0.1f
#define SLOTS    12      // positive slots per (row, col-block); lambda=1.28 -> P(overflow)~1e-9

typedef __attribute__((ext_vector_type(8))) short short8;
typedef __attribute__((ext_vector_type(4))) float f32x4;
typedef __attribute__((ext_vector_type(2))) float f32x2;

__device__ __forceinline__ void gload_lds16(const void* gsrc, void* ldst) {
    __builtin_amdgcn_global_load_lds(
        (const __attribute__((address_space(1))) void*)gsrc,
        (__attribute__((address_space(3))) void*)ldst, 16, 0, 0);
}

// inputs_norm * SCALE -> bf16 A [1024][256]; one block (256 thr) per row
__global__ void anorm_kernel(const float* __restrict__ in, __hip_bfloat16* __restrict__ A) {
    int b = blockIdx.x, t = threadIdx.x;
    float x = in[b * FDIM + t];
    float ss = x * x;
    #pragma unroll
    for (int o = 32; o > 0; o >>= 1) ss += __shfl_xor(ss, o);
    __shared__ float sh[4];
    if ((t & 63) == 0) sh[t >> 6] = ss;
    __syncthreads();
    float tot = sh[0] + sh[1] + sh[2] + sh[3];
    float r = SCALEF / fmaxf(sqrtf(tot), 1e-12f);
    A[b * FDIM + t] = __float2bfloat16(x * r);
}

// scatter-mean (gather form) + l2-normalize -> bf16 B [CPAD][256]; block per clothes id
__global__ void bnorm_kernel(const float* __restrict__ fm, const float* __restrict__ in,
                             const int* __restrict__ tg, __hip_bfloat16* __restrict__ Bm) {
    int c = blockIdx.x, t = threadIdx.x;
    __shared__ int stg[NBATCH];
    if (c < NCLOTHES) {
        #pragma unroll
        for (int j = 0; j < 4; ++j) stg[t + j * 256] = tg[t + j * 256];
    }
    if (c >= NCLOTHES) { Bm[(size_t)c * FDIM + t] = __float2bfloat16(0.f); return; }
    __shared__ int mlist[32];
    __shared__ int mcount;
    if (t == 0) mcount = 0;
    __syncthreads();
    #pragma unroll
    for (int j = 0; j < 4; ++j) {
        int b = t + j * 256;
        if (stg[b] == c) { int p = atomicAdd(&mcount, 1); if (p < 32) mlist[p] = b; }
    }
    __syncthreads();
    int n = mcount;
    float v;
    if (n == 0) {
        v = fm[(size_t)c * FDIM + t];
    } else {
        v = 0.f;
        for (int i = 0; i < n; ++i) v += in[mlist[i] * FDIM + t];
        v /= (float)n;
    }
    float ss = v * v;
    #pragma unroll
    for (int o = 32; o > 0; o >>= 1) ss += __shfl_xor(ss, o);
    __shared__ float sh[4];
    if ((t & 63) == 0) sh[t >> 6] = ss;
    __syncthreads();
    float tot = sh[0] + sh[1] + sh[2] + sh[3];
    float r = 1.0f / fmaxf(sqrtf(tot), 1e-12f);
    Bm[(size_t)c * FDIM + t] = __float2bfloat16(v * r);
}

// Fused GEMM: sims tile [128x128]; epilogue: wave-per-row, coalesced pm, NO global atomics.
#define BM 128
#define BN 128
#define BK 32
#define NKSTEP (FDIM / BK)

__global__ __launch_bounds__(256, 3)
void gemm_kernel(const __hip_bfloat16* __restrict__ A, const __hip_bfloat16* __restrict__ Bm,
                 const float* __restrict__ pm,
                 float* __restrict__ partial_ns,      // [NBATCH][NCB]
                 unsigned int* __restrict__ cnt,      // [NBATCH][NCB]
                 float* __restrict__ sbuf,            // [NBATCH][NCB][SLOTS]
                 unsigned char* __restrict__ colbuf)  // [NBATCH][NCB][SLOTS]
{
    __shared__ alignas(16) char smem[32768];
    __hip_bfloat16* As0 = (__hip_bfloat16*)smem;            // As[2][BM*BK], 16 KB
    __hip_bfloat16* Bs0 = (__hip_bfloat16*)(smem + 16384);  // Bs[2][BM*BK], 16 KB
    float* sims = (float*)smem;                             // [32][132] f32, 16.9 KB overlay

    const int t = threadIdx.x;
    const int bx = blockIdx.x;
    const int bn0 = bx * BN;
    const int bm0 = blockIdx.y * BM;

    const int lane = t & 63;
    const int wave = t >> 6;
    const int wr = wave >> 1, wc = wave & 1;
    const int lrow = lane & 15, lq = lane >> 4;

    const int sr = t >> 2;            // staging row 0..63
    const int sk = (t & 3) * 8;       // staging k chunk

    // epilogue coordinates: one wave owns one sims row per iteration
    const int tcol2 = lane * 2;                 // 0..126
    const int gcolw = bn0 + tcol2;
    const bool valid = (gcolw < NCLOTHES);      // covers both cols (even boundary)
    const unsigned long long lmask = (lane == 63) ? ~0ull : ((1ull << (lane + 1)) - 1ull) >> 1;

    f32x4 acc[4][4];
    #pragma unroll
    for (int m = 0; m < 4; ++m)
        #pragma unroll
        for (int n = 0; n < 4; ++n) acc[m][n] = (f32x4)0.f;

    // prefetch pm chunk 0 (8 rows per wave), hidden under K-loop
    f32x2 pmA[8], pmB[8];
    #pragma unroll
    for (int j = 0; j < 8; ++j) {
        int grow = bm0 + wave * 8 + j;
        pmA[j] = valid ? *(const f32x2*)(pm + (size_t)grow * NCLOTHES + gcolw) : (f32x2)0.f;
    }

    // stage k-step 0 into buffer 0
    {
        const __hip_bfloat16* ag = A + (size_t)(bm0 + sr) * FDIM + sk;
        const __hip_bfloat16* bg = Bm + (size_t)(bn0 + sr) * FDIM + sk;
        gload_lds16(ag,             (void*)&As0[t * 8]);
        gload_lds16(ag + 64 * FDIM, (void*)&As0[2048 + t * 8]);
        gload_lds16(bg,             (void*)&Bs0[t * 8]);
        gload_lds16(bg + 64 * FDIM, (void*)&Bs0[2048 + t * 8]);
    }

    for (int ks = 0; ks < NKSTEP; ++ks) {
        __syncthreads();
        int cur = ks & 1;
        if (ks + 1 < NKSTEP) {
            int nxt = cur ^ 1;
            int k0 = (ks + 1) * BK;
            const __hip_bfloat16* ag = A + (size_t)(bm0 + sr) * FDIM + k0 + sk;
            const __hip_bfloat16* bg = Bm + (size_t)(bn0 + sr) * FDIM + k0 + sk;
            gload_lds16(ag,             (void*)&As0[nxt * 4096 + t * 8]);
            gload_lds16(ag + 64 * FDIM, (void*)&As0[nxt * 4096 + 2048 + t * 8]);
            gload_lds16(bg,             (void*)&Bs0[nxt * 4096 + t * 8]);
            gload_lds16(bg + 64 * FDIM, (void*)&Bs0[nxt * 4096 + 2048 + t * 8]);
        }
        short8 af[4], bf[4];
        #pragma unroll
        for (int m = 0; m < 4; ++m)
            af[m] = *(const short8*)&As0[cur * 4096 + (wr * 64 + m * 16 + lrow) * BK + lq * 8];
        #pragma unroll
        for (int n = 0; n < 4; ++n)
            bf[n] = *(const short8*)&Bs0[cur * 4096 + (wc * 64 + n * 16 + lrow) * BK + lq * 8];
        #pragma unroll
        for (int m = 0; m < 4; ++m)
            #pragma unroll
            for (int n = 0; n < 4; ++n)
                acc[m][n] = __builtin_amdgcn_mfma_f32_16x16x32_bf16(af[m], bf[n], acc[m][n], 0, 0, 0);
    }

    __syncthreads();   // all MFMA LDS reads done before overlaying sims

    // 4 chunks of 32 rows. acc C/D layout: tile row = wr*64 + m*16 + lq*4 + r, col = wc*64 + n*16 + lrow
    #pragma unroll
    for (int c = 0; c < 4; ++c) {
        if (wr == (c >> 1)) {
            #pragma unroll
            for (int mm = 0; mm < 2; ++mm) {
                int m = (c & 1) * 2 + mm;
                #pragma unroll
                for (int n = 0; n < 4; ++n) {
                    int col = wc * 64 + n * 16 + lrow;
                    #pragma unroll
                    for (int r = 0; r < 4; ++r)
                        sims[(mm * 16 + lq * 4 + r) * 132 + col] = acc[m][n][r];
                }
            }
        }
        // prefetch next chunk's pm into the other register bank
        if (c < 3) {
            #pragma unroll
            for (int j = 0; j < 8; ++j) {
                int grow = bm0 + (c + 1) * 32 + wave * 8 + j;
                f32x2 v = valid ? *(const f32x2*)(pm + (size_t)grow * NCLOTHES + gcolw) : (f32x2)0.f;
                if (c & 1) pmA[j] = v; else pmB[j] = v;
            }
        }
        __syncthreads();
        #pragma unroll
        for (int j = 0; j < 8; ++j) {
            int row = wave * 8 + j;               // row within chunk
            int grow = bm0 + c * 32 + row;
            f32x2 s2 = *(const f32x2*)&sims[row * 132 + tcol2];
            f32x2 p2 = (c & 1) ? pmB[j] : pmA[j];
            float e0 = __expf(s2.x), e1 = __expf(s2.y);
            bool pos0 = valid && (p2.x >= 0.5f);
            bool pos1 = valid && (p2.y >= 0.5f);
            float pneg = valid ? ((pos0 ? 0.f : e0) + (pos1 ? 0.f : e1)) : 0.f;
            #pragma unroll
            for (int o = 32; o > 0; o >>= 1) pneg += __shfl_xor(pneg, o);
            unsigned long long b0 = __ballot(pos0);
            unsigned long long b1 = __ballot(pos1);
            int c0 = __popcll(b0);
            int pre0 = __popcll(b0 & lmask);
            int pre1 = c0 + __popcll(b1 & lmask);
            size_t idx = (size_t)grow * NCB + bx;
            if (pos0 && pre0 < SLOTS) {
                sbuf[idx * SLOTS + pre0] = s2.x;
                colbuf[idx * SLOTS + pre0] = (unsigned char)tcol2;
            }
            if (pos1 && pre1 < SLOTS) {
                sbuf[idx * SLOTS + pre1] = s2.y;
                colbuf[idx * SLOTS + pre1] = (unsigned char)(tcol2 + 1);
            }
            if (lane == 0) {
                int ctot = c0 + __popcll(b1);
                cnt[idx] = (unsigned int)(ctot < SLOTS ? ctot : SLOTS);
                partial_ns[idx] = pneg;
            }
        }
        __syncthreads();
    }
}

__global__ void finish_kernel(const float* __restrict__ partial_ns, const unsigned int* __restrict__ cnt,
                              const float* __restrict__ sbuf, const unsigned char* __restrict__ colbuf,
                              const int* __restrict__ tg, float* __restrict__ loss_rows) {
    int b = blockIdx.x, t = threadIdx.x;
    int tgt = tg[b];
    float ns = 0.f;
    int np = 0;
    for (int cb = t; cb < NCB; cb += 256) {
        size_t idx = (size_t)b * NCB + cb;
        ns += partial_ns[idx];
        np += (int)cnt[idx];
    }
    #pragma unroll
    for (int o = 32; o > 0; o >>= 1) { ns += __shfl_xor(ns, o); np += __shfl_xor(np, o); }
    __shared__ float shn[4]; __shared__ int shp[4];
    if ((t & 63) == 0) { shn[t >> 6] = ns; shp[t >> 6] = np; }
    __syncthreads();
    ns = shn[0] + shn[1] + shn[2] + shn[3];
    np = shp[0] + shp[1] + shp[2] + shp[3];

    float slp = 0.f, idlp = 0.f;
    for (int cb = t; cb < NCB; cb += 256) {
        size_t idx = (size_t)b * NCB + cb;
        int k = (int)cnt[idx];
        for (int i = 0; i < k; ++i) {
            float s = sbuf[idx * SLOTS + i];
            int col = cb * 128 + (int)colbuf[idx * SLOTS + i];
            float lp = s - __logf(ns + __expf(s));
            slp += lp;
            if (col == tgt) idlp += lp;
        }
    }
    #pragma unroll
    for (int o = 32; o > 0; o >>= 1) { slp += __shfl_xor(slp, o); idlp += __shfl_xor(idlp, o); }
    __shared__ float sh1[4], sh2[4];
    if ((t & 63) == 0) { sh1[t >> 6] = slp; sh2[t >> 6] = idlp; }
    __syncthreads();
    if (t == 0) {
        float s_all = sh1[0] + sh1[1] + sh1[2] + sh1[3];
        float i_all = sh2[0] + sh2[1] + sh2[2] + sh2[3];
        loss_rows[b] = -((1.0f - EPSW) * i_all + (EPSW / (float)np) * s_all);
    }
}

__global__ void reduce_kernel(const float* __restrict__ lr, float* __restrict__ out) {
    int t = threadIdx.x;
    float s = lr[t] + lr[t + 256] + lr[t + 512] + lr[t + 768];
    #pragma unroll
    for (int o = 32; o > 0; o >>= 1) s += __shfl_xor(s, o);
    __shared__ float sh[4];
    if ((t & 63) == 0) sh[t >> 6] = s;
    __syncthreads();
    if (t == 0) out[0] = (sh[0] + sh[1] + sh[2] + sh[3]) * (1.0f / NBATCH);
}

extern "C" void kernel_launch(void* const* d_in, const int* in_sizes, int n_in,
                              void* d_out, int out_size, void* d_ws, size_t ws_size,
                              hipStream_t stream) {
    const float* inputs  = (const float*)d_in[0];
    const float* fm      = (const float*)d_in[1];
    const float* pmask   = (const float*)d_in[2];
    const int*   targets = (const int*)d_in[3];
    float* out = (float*)d_out;

    char* ws = (char*)d_ws;
    size_t off = 0;
    __hip_bfloat16* A = (__hip_bfloat16*)(ws + off);  off += (size_t)NBATCH * FDIM * 2;        // 512 KB
    __hip_bfloat16* Bm = (__hip_bfloat16*)(ws + off); off += (size_t)CPAD * FDIM * 2;          // 25.6 MB
    off = (off + 255) & ~(size_t)255;
    float* partial_ns = (float*)(ws + off);      off += (size_t)NBATCH * NCB * 4;              // 1.6 MB
    unsigned int* cnt = (unsigned int*)(ws + off); off += (size_t)NBATCH * NCB * 4;            // 1.6 MB
    float* sbuf = (float*)(ws + off);            off += (size_t)NBATCH * NCB * SLOTS * 4;      // 19.2 MB
    unsigned char* colbuf = (unsigned char*)(ws + off); off += (size_t)NBATCH * NCB * SLOTS;   // 4.8 MB
    off = (off + 255) & ~(size_t)255;
    float* loss_rows = (float*)(ws + off);       off += 4096;

    anorm_kernel<<<NBATCH, 256, 0, stream>>>(inputs, A);
    bnorm_kernel<<<CPAD, 256, 0, stream>>>(fm, inputs, targets, Bm);
    gemm_kernel<<<dim3(NCB, NBATCH / BM), 256, 0, stream>>>(A, Bm, pmask, partial_ns, cnt, sbuf, colbuf);
    finish_kernel<<<NBATCH, 256, 0, stream>>>(partial_ns, cnt, sbuf, colbuf, targets, loss_rows);
    reduce_kernel<<<1, 256, 0, stream>>>(loss_rows, out);
}

// Round 4
// 411.742 us; speedup vs baseline: 2.4247x; 1.0188x over previous
//
#include <hip/hip_runtime.h>
#include <hip/hip_bf16.h>
#include <stdint.h>

#define NCLOTHES 50000
#define CPAD     50048   // 391 * 128
#define NCB      391     // 128-col blocks
#define NCB2     782     // 64-col half-blocks (one per (bx, wc))
#define FDIM     256
#define NBATCH   1024
#define SCALEF   16.0f
#define EPSW     0.1f
#define SLOTS    8       // positive slots per (row, 64-col half); lambda=0.64

typedef __attribute__((ext_vector_type(8))) short short8;
typedef __attribute__((ext_vector_type(4))) float f32x4;

__device__ __forceinline__ void gload_lds16(const void* gsrc, void* ldst) {
    __builtin_amdgcn_global_load_lds(
        (const __attribute__((address_space(1))) void*)gsrc,
        (__attribute__((address_space(3))) void*)ldst, 16, 0, 0);
}

// inputs_norm * SCALE -> bf16 A [1024][256]; one block (256 thr) per row
__global__ void anorm_kernel(const float* __restrict__ in, __hip_bfloat16* __restrict__ A) {
    int b = blockIdx.x, t = threadIdx.x;
    float x = in[b * FDIM + t];
    float ss = x * x;
    #pragma unroll
    for (int o = 32; o > 0; o >>= 1) ss += __shfl_xor(ss, o);
    __shared__ float sh[4];
    if ((t & 63) == 0) sh[t >> 6] = ss;
    __syncthreads();
    float tot = sh[0] + sh[1] + sh[2] + sh[3];
    float r = SCALEF / fmaxf(sqrtf(tot), 1e-12f);
    A[b * FDIM + t] = __float2bfloat16(x * r);
}

// normalize ALL feature_memory rows -> bf16 B; wave-per-row streaming, grid-stride
__global__ __launch_bounds__(256)
void bnorm_all(const float* __restrict__ fm, __hip_bfloat16* __restrict__ Bm) {
    const int nw = (gridDim.x * 256) >> 6;
    int w = (blockIdx.x * 256 + threadIdx.x) >> 6;
    int lane = threadIdx.x & 63;
    for (int row = w; row < CPAD; row += nw) {
        __hip_bfloat16 h[4];
        if (row >= NCLOTHES) {
            h[0] = h[1] = h[2] = h[3] = __float2bfloat16(0.f);
        } else {
            f32x4 v = *(const f32x4*)(fm + (size_t)row * FDIM + lane * 4);
            float ss = v.x * v.x + v.y * v.y + v.z * v.z + v.w * v.w;
            #pragma unroll
            for (int o = 32; o > 0; o >>= 1) ss += __shfl_xor(ss, o);
            float r = 1.f / fmaxf(sqrtf(ss), 1e-12f);
            h[0] = __float2bfloat16(v.x * r);
            h[1] = __float2bfloat16(v.y * r);
            h[2] = __float2bfloat16(v.z * r);
            h[3] = __float2bfloat16(v.w * r);
        }
        *(ushort4*)(Bm + (size_t)row * FDIM + lane * 4) = *(const ushort4*)h;
    }
}

// overwrite the <=1024 present clothes rows with normalized scatter-mean
__global__ void bnorm_present(const float* __restrict__ in, const int* __restrict__ tg,
                              __hip_bfloat16* __restrict__ Bm) {
    int b = blockIdx.x, t = threadIdx.x;
    __shared__ int stg[NBATCH];
    #pragma unroll
    for (int j = 0; j < 4; ++j) stg[t + j * 256] = tg[t + j * 256];
    __syncthreads();
    int c = stg[b];
    // dedup: only the first batch index with this clothes id does the work
    bool dup = false;
    #pragma unroll
    for (int j = 0; j < 4; ++j) {
        int i = t + j * 256;
        if (i < b && stg[i] == c) dup = true;
    }
    if (__syncthreads_or(dup)) return;
    __shared__ int mlist[64];
    __shared__ int mcount;
    if (t == 0) mcount = 0;
    __syncthreads();
    #pragma unroll
    for (int j = 0; j < 4; ++j) {
        int i = t + j * 256;
        if (stg[i] == c) { int p = atomicAdd(&mcount, 1); if (p < 64) mlist[p] = i; }
    }
    __syncthreads();
    int n = mcount;
    float v = 0.f;
    for (int i = 0; i < n; ++i) v += in[mlist[i] * FDIM + t];
    v /= (float)n;
    float ss = v * v;
    #pragma unroll
    for (int o = 32; o > 0; o >>= 1) ss += __shfl_xor(ss, o);
    __shared__ float sh[4];
    if ((t & 63) == 0) sh[t >> 6] = ss;
    __syncthreads();
    float tot = sh[0] + sh[1] + sh[2] + sh[3];
    float r = 1.0f / fmaxf(sqrtf(tot), 1e-12f);
    Bm[(size_t)c * FDIM + t] = __float2bfloat16(v * r);
}

// Fused GEMM with barrier-free register-direct epilogue. No atomics, no epilogue LDS.
#define BM 128
#define BN 128
#define BK 32
#define NKSTEP (FDIM / BK)

__global__ __launch_bounds__(256, 4)
void gemm_kernel(const __hip_bfloat16* __restrict__ A, const __hip_bfloat16* __restrict__ Bm,
                 const float* __restrict__ pm,
                 float* __restrict__ partial_ns,      // [NBATCH][NCB2]
                 unsigned int* __restrict__ cnt,      // [NBATCH][NCB2]
                 float* __restrict__ sbuf,            // [NBATCH][NCB2][SLOTS]
                 unsigned char* __restrict__ colbuf)  // [NBATCH][NCB2][SLOTS], local col 0..63
{
    __shared__ alignas(16) __hip_bfloat16 As[2][BM * BK];
    __shared__ alignas(16) __hip_bfloat16 Bs[2][BM * BK];

    const int t = threadIdx.x;
    const int bx = blockIdx.x;
    const int bn0 = bx * BN;
    const int bm0 = blockIdx.y * BM;

    const int lane = t & 63;
    const int wave = t >> 6;
    const int wr = wave >> 1, wc = wave & 1;
    const int lrow = lane & 15, lq = lane >> 4;

    const int sr = t >> 2;            // staging row 0..63
    const int sk = (t & 3) * 8;       // staging k chunk

    f32x4 acc[4][4];
    #pragma unroll
    for (int m = 0; m < 4; ++m)
        #pragma unroll
        for (int n = 0; n < 4; ++n) acc[m][n] = (f32x4)0.f;

    // stage k-step 0 into buffer 0
    {
        const __hip_bfloat16* ag = A + (size_t)(bm0 + sr) * FDIM + sk;
        const __hip_bfloat16* bg = Bm + (size_t)(bn0 + sr) * FDIM + sk;
        gload_lds16(ag,             (void*)&As[0][t * 8]);
        gload_lds16(ag + 64 * FDIM, (void*)&As[0][2048 + t * 8]);
        gload_lds16(bg,             (void*)&Bs[0][t * 8]);
        gload_lds16(bg + 64 * FDIM, (void*)&Bs[0][2048 + t * 8]);
    }

    for (int ks = 0; ks < NKSTEP; ++ks) {
        __syncthreads();
        int cur = ks & 1;
        if (ks + 1 < NKSTEP) {
            int nxt = cur ^ 1;
            int k0 = (ks + 1) * BK;
            const __hip_bfloat16* ag = A + (size_t)(bm0 + sr) * FDIM + k0 + sk;
            const __hip_bfloat16* bg = Bm + (size_t)(bn0 + sr) * FDIM + k0 + sk;
            gload_lds16(ag,             (void*)&As[nxt][t * 8]);
            gload_lds16(ag + 64 * FDIM, (void*)&As[nxt][2048 + t * 8]);
            gload_lds16(bg,             (void*)&Bs[nxt][t * 8]);
            gload_lds16(bg + 64 * FDIM, (void*)&Bs[nxt][2048 + t * 8]);
        }
        short8 af[4], bf[4];
        #pragma unroll
        for (int m = 0; m < 4; ++m)
            af[m] = *(const short8*)&As[cur][(wr * 64 + m * 16 + lrow) * BK + lq * 8];
        #pragma unroll
        for (int n = 0; n < 4; ++n)
            bf[n] = *(const short8*)&Bs[cur][(wc * 64 + n * 16 + lrow) * BK + lq * 8];
        #pragma unroll
        for (int m = 0; m < 4; ++m)
            #pragma unroll
            for (int n = 0; n < 4; ++n)
                acc[m][n] = __builtin_amdgcn_mfma_f32_16x16x32_bf16(af[m], bf[n], acc[m][n], 0, 0, 0);
    }

    // ---- register-direct epilogue (no barriers, no LDS, no atomics) ----
    // acc C/D layout: tile row = wr*64 + m*16 + lq*4 + r, col = wc*64 + n*16 + lrow
    const int cb2 = bx * 2 + wc;              // 64-col half-block index
    const int colbase = bn0 + wc * 64;        // global col of local col 0

    #pragma unroll
    for (int m = 0; m < 4; ++m) {
        #pragma unroll
        for (int r = 0; r < 4; ++r) {
            const int grow = bm0 + wr * 64 + m * 16 + lq * 4 + r;
            const float* prow = pm + (size_t)grow * NCLOTHES + colbase + lrow;
            float pv[4];
            #pragma unroll
            for (int n = 0; n < 4; ++n) pv[n] = prow[n * 16];   // memory-safe even at tail
            float pneg = 0.f;
            unsigned posn = 0;
            #pragma unroll
            for (int n = 0; n < 4; ++n) {
                bool valid = (colbase + n * 16 + lrow) < NCLOTHES;
                bool pos = valid && (pv[n] >= 0.5f);
                if (pos) posn |= (1u << n);
                pneg += (valid && !pos) ? __expf(acc[m][n][r]) : 0.f;
            }
            pneg += __shfl_xor(pneg, 1);
            pneg += __shfl_xor(pneg, 2);
            pneg += __shfl_xor(pneg, 4);
            pneg += __shfl_xor(pneg, 8);
            const size_t idx = (size_t)grow * NCB2 + cb2;
            int slot_base = 0;
            #pragma unroll
            for (int n = 0; n < 4; ++n) {
                unsigned long long bal = __ballot((posn >> n) & 1);
                unsigned seg = (unsigned)((bal >> (lq * 16)) & 0xFFFFull);
                int pre = slot_base + __popc(seg & ((1u << lrow) - 1u));
                if (((posn >> n) & 1) && pre < SLOTS) {
                    sbuf[idx * SLOTS + pre] = acc[m][n][r];
                    colbuf[idx * SLOTS + pre] = (unsigned char)(n * 16 + lrow);
                }
                slot_base += __popc(seg);
            }
            if (lrow == 0) {
                cnt[idx] = (unsigned int)(slot_base < SLOTS ? slot_base : SLOTS);
                partial_ns[idx] = pneg;
            }
        }
    }
}

__global__ void finish_kernel(const float* __restrict__ partial_ns, const unsigned int* __restrict__ cnt,
                              const float* __restrict__ sbuf, const unsigned char* __restrict__ colbuf,
                              const int* __restrict__ tg, float* __restrict__ loss_rows) {
    int b = blockIdx.x, t = threadIdx.x;
    int tgt = tg[b];
    float ns = 0.f;
    int np = 0;
    for (int cb = t; cb < NCB2; cb += 256) {
        size_t idx = (size_t)b * NCB2 + cb;
        ns += partial_ns[idx];
        np += (int)cnt[idx];
    }
    #pragma unroll
    for (int o = 32; o > 0; o >>= 1) { ns += __shfl_xor(ns, o); np += __shfl_xor(np, o); }
    __shared__ float shn[4]; __shared__ int shp[4];
    if ((t & 63) == 0) { shn[t >> 6] = ns; shp[t >> 6] = np; }
    __syncthreads();
    ns = shn[0] + shn[1] + shn[2] + shn[3];
    np = shp[0] + shp[1] + shp[2] + shp[3];

    float slp = 0.f, idlp = 0.f;
    for (int cb = t; cb < NCB2; cb += 256) {
        size_t idx = (size_t)b * NCB2 + cb;
        int k = (int)cnt[idx];
        for (int i = 0; i < k; ++i) {
            float s = sbuf[idx * SLOTS + i];
            int col = cb * 64 + (int)colbuf[idx * SLOTS + i];
            float lp = s - __logf(ns + __expf(s));
            slp += lp;
            if (col == tgt) idlp += lp;
        }
    }
    #pragma unroll
    for (int o = 32; o > 0; o >>= 1) { slp += __shfl_xor(slp, o); idlp += __shfl_xor(idlp, o); }
    __shared__ float sh1[4], sh2[4];
    if ((t & 63) == 0) { sh1[t >> 6] = slp; sh2[t >> 6] = idlp; }
    __syncthreads();
    if (t == 0) {
        float s_all = sh1[0] + sh1[1] + sh1[2] + sh1[3];
        float i_all = sh2[0] + sh2[1] + sh2[2] + sh2[3];
        loss_rows[b] = -((1.0f - EPSW) * i_all + (EPSW / (float)np) * s_all);
    }
}

__global__ void reduce_kernel(const float* __restrict__ lr, float* __restrict__ out) {
    int t = threadIdx.x;
    float s = lr[t] + lr[t + 256] + lr[t + 512] + lr[t + 768];
    #pragma unroll
    for (int o = 32; o > 0; o >>= 1) s += __shfl_xor(s, o);
    __shared__ float sh[4];
    if ((t & 63) == 0) sh[t >> 6] = s;
    __syncthreads();
    if (t == 0) out[0] = (sh[0] + sh[1] + sh[2] + sh[3]) * (1.0f / NBATCH);
}

extern "C" void kernel_launch(void* const* d_in, const int* in_sizes, int n_in,
                              void* d_out, int out_size, void* d_ws, size_t ws_size,
                              hipStream_t stream) {
    const float* inputs  = (const float*)d_in[0];
    const float* fm      = (const float*)d_in[1];
    const float* pmask   = (const float*)d_in[2];
    const int*   targets = (const int*)d_in[3];
    float* out = (float*)d_out;

    char* ws = (char*)d_ws;
    size_t off = 0;
    __hip_bfloat16* A = (__hip_bfloat16*)(ws + off);  off += (size_t)NBATCH * FDIM * 2;        // 512 KB
    __hip_bfloat16* Bm = (__hip_bfloat16*)(ws + off); off += (size_t)CPAD * FDIM * 2;          // 25.6 MB
    off = (off + 255) & ~(size_t)255;
    float* partial_ns = (float*)(ws + off);        off += (size_t)NBATCH * NCB2 * 4;           // 3.2 MB
    unsigned int* cnt = (unsigned int*)(ws + off); off += (size_t)NBATCH * NCB2 * 4;           // 3.2 MB
    float* sbuf = (float*)(ws + off);              off += (size_t)NBATCH * NCB2 * SLOTS * 4;   // 25.6 MB
    unsigned char* colbuf = (unsigned char*)(ws + off); off += (size_t)NBATCH * NCB2 * SLOTS;  // 6.4 MB
    off = (off + 255) & ~(size_t)255;
    float* loss_rows = (float*)(ws + off);         off += 4096;

    anorm_kernel<<<NBATCH, 256, 0, stream>>>(inputs, A);
    bnorm_all<<<2048, 256, 0, stream>>>(fm, Bm);
    bnorm_present<<<NBATCH, 256, 0, stream>>>(inputs, targets, Bm);
    gemm_kernel<<<dim3(NCB, NBATCH / BM), 256, 0, stream>>>(A, Bm, pmask, partial_ns, cnt, sbuf, colbuf);
    finish_kernel<<<NBATCH, 256, 0, stream>>>(partial_ns, cnt, sbuf, colbuf, targets, loss_rows);
    reduce_kernel<<<1, 256, 0, stream>>>(loss_rows, out);
}